// Round 3
// baseline (447.936 us; speedup 1.0000x reference)
//
#include <hip/hip_runtime.h>

// ---------- types / helpers ----------
typedef __attribute__((ext_vector_type(8))) short short8;   // 8 x bf16 (4 VGPRs)
typedef __attribute__((ext_vector_type(4))) float floatx4;  // MFMA acc / 16B fp32 load

__device__ __forceinline__ unsigned short f2bf(float f) {
  unsigned u = __float_as_uint(f);
  u += 0x7FFFu + ((u >> 16) & 1u);          // round-to-nearest-even
  return (unsigned short)(u >> 16);
}
__device__ __forceinline__ float bf2f(unsigned short s) {
  return __uint_as_float(((unsigned)s) << 16);
}

#define B_   2
#define QN_  2048
#define NDS_ 1024
#define H_   16
#define DH_  64

// ---------- dtype detection ----------
// Wq values are ~N(0,1)*0.02 (|x| <= ~0.12). If the buffer is bf16, every u16
// has exponent field <= ~0x7C. If it is fp32, the low half of each float is
// random mantissa bits -> ~half of those u16s have exponent >= 0x7F.
__global__ __launch_bounds__(256) void detect_dtype(
    const unsigned short* __restrict__ Wq, int* __restrict__ flag) {
  __shared__ int smax[256];
  int t = threadIdx.x;
  int m = 0;
  for (int i = t; i < 4096; i += 256) {
    int e = (Wq[i] >> 7) & 0xFF;
    m = m > e ? m : e;
  }
  smax[t] = m;
  __syncthreads();
  for (int s = 128; s > 0; s >>= 1) {
    if (t < s) smax[t] = smax[t] > smax[t + s] ? smax[t] : smax[t + s];
    __syncthreads();
  }
  if (t == 0) *flag = (smax[0] >= 0x7F) ? 1 : 0;  // 1 = inputs are fp32
}

// ---------- C[M,N] = A[M,K] @ W[K,N] (+bias), fp32 acc ----------
// ADYN: A dtype follows flag (input activations). ODYN: C dtype follows flag
// (writes d_out). W/bias are model inputs -> always follow flag. Intermediates
// in ws are always bf16. 128x128 tile / 256 threads, BK=32.
template <int ADYN, int ODYN>
__global__ __launch_bounds__(256) void gemm_aw(
    const void* __restrict__ A, const void* __restrict__ W,
    void* __restrict__ C, const void* __restrict__ bias,
    int M, int N, int K, const int* __restrict__ flagp) {
  __shared__ __align__(16) unsigned short As[128 * 32];
  __shared__ __align__(16) unsigned short Wt[128 * 32];
  const int f32 = *flagp;
  int t = threadIdx.x;
  int lane = t & 63, wave = t >> 6;
  int lrow = lane & 15, quad = lane >> 4;
  int rowBase = blockIdx.y * 128;
  int colBase = blockIdx.x * 128;
  int wr = (wave & 1) * 64, wc = (wave >> 1) * 64;
  int kr = t & 31, rg = t >> 5;

  floatx4 acc[4][4];
#pragma unroll
  for (int mi = 0; mi < 4; ++mi)
#pragma unroll
    for (int ni = 0; ni < 4; ++ni) acc[mi][ni] = (floatx4){0.f, 0.f, 0.f, 0.f};

  for (int k0 = 0; k0 < K; k0 += 32) {
    __syncthreads();
    // stage A tile [128][32]
#pragma unroll
    for (int it = 0; it < 2; ++it) {
      int linear = it * 256 + t;  // 8-elem chunk id, 0..511
      int row = linear >> 2, seg = linear & 3;
      size_t idx = (size_t)(rowBase + row) * K + k0 + seg * 8;
      short8 v;
      if (ADYN && f32) {
        const floatx4* p = (const floatx4*)((const float*)A + idx);
        floatx4 f0 = p[0], f1 = p[1];
#pragma unroll
        for (int e = 0; e < 4; ++e) { v[e] = (short)f2bf(f0[e]); v[4 + e] = (short)f2bf(f1[e]); }
      } else {
        v = *(const short8*)((const unsigned short*)A + idx);
      }
      *(short8*)&As[linear * 8] = v;
    }
    // stage W tile transposed: Wt[col][k] = W[k0+k][colBase+col]
#pragma unroll
    for (int half = 0; half < 2; ++half) {
      size_t idx = (size_t)(k0 + kr) * N + colBase + rg * 16 + half * 8;
      short8 w;
      if (f32) {
        const floatx4* p = (const floatx4*)((const float*)W + idx);
        floatx4 f0 = p[0], f1 = p[1];
#pragma unroll
        for (int e = 0; e < 4; ++e) { w[e] = (short)f2bf(f0[e]); w[4 + e] = (short)f2bf(f1[e]); }
      } else {
        w = *(const short8*)((const unsigned short*)W + idx);
      }
#pragma unroll
      for (int e = 0; e < 8; ++e)
        Wt[(rg * 16 + half * 8 + e) * 32 + kr] = (unsigned short)w[e];
    }
    __syncthreads();

    short8 af[4], bfr[4];
#pragma unroll
    for (int mi = 0; mi < 4; ++mi)
      af[mi] = *(const short8*)&As[(wr + mi * 16 + lrow) * 32 + quad * 8];
#pragma unroll
    for (int ni = 0; ni < 4; ++ni)
      bfr[ni] = *(const short8*)&Wt[(wc + ni * 16 + lrow) * 32 + quad * 8];
#pragma unroll
    for (int mi = 0; mi < 4; ++mi)
#pragma unroll
      for (int ni = 0; ni < 4; ++ni)
        acc[mi][ni] =
            __builtin_amdgcn_mfma_f32_16x16x32_bf16(af[mi], bfr[ni], acc[mi][ni], 0, 0, 0);
  }

#pragma unroll
  for (int mi = 0; mi < 4; ++mi)
#pragma unroll
    for (int ni = 0; ni < 4; ++ni) {
      int col = colBase + wc + ni * 16 + lrow;
      float badd = 0.f;
      if (ODYN && bias)
        badd = f32 ? ((const float*)bias)[col] : bf2f(((const unsigned short*)bias)[col]);
#pragma unroll
      for (int r = 0; r < 4; ++r) {
        int row = rowBase + wr + mi * 16 + quad * 4 + r;
        float val = acc[mi][ni][r] + badd;
        size_t oidx = (size_t)row * N + col;
        if (ODYN && f32) ((float*)C)[oidx] = val;
        else ((unsigned short*)C)[oidx] = f2bf(val);
      }
    }
}

// ---------- attention over unique keys with duplicate-multiplier ----------
// Keys tiled twice in the reference: softmax over 2048 duplicated keys ==
// softmax over 1024 unique keys with multiplier m(i,j0) in {0,1,2}.
// All operands are bf16 intermediates in ws. grid (QN/64, B*H).
__global__ __launch_bounds__(256) void attn_kernel(
    const unsigned short* __restrict__ Q,   // [B*QN][1024]
    const unsigned short* __restrict__ K,   // [B*NDS][1024]
    const unsigned short* __restrict__ V,   // [B*NDS][1024]
    unsigned short* __restrict__ O) {       // [B*QN][1024]
  __shared__ __align__(16) unsigned short lds[4 * (64 * 32 + 16 * 32)];
  int t = threadIdx.x, lane = t & 63, wave = t >> 6;
  unsigned short* Vt = lds + wave * (64 * 32 + 16 * 32);
  unsigned short* P = Vt + 64 * 32;
  int lrow = lane & 15, quad = lane >> 4;
  int bh = blockIdx.y, b = bh >> 4, h = bh & 15;
  int qtile = blockIdx.x * 64 + wave * 16;

  const unsigned short* qptr =
      Q + (size_t)(b * QN_ + qtile + lrow) * 1024 + h * 64 + quad * 8;
  short8 qa0 = *(const short8*)qptr;
  short8 qa1 = *(const short8*)(qptr + 32);

  floatx4 acc_o[4];
#pragma unroll
  for (int dt = 0; dt < 4; ++dt) acc_o[dt] = (floatx4){0.f, 0.f, 0.f, 0.f};
  float denom[4] = {0.f, 0.f, 0.f, 0.f};

  for (int c = 0; c < NDS_ / 32; ++c) {
    {  // stage V chunk transposed: Vt[d][kv]
      int jj = lane & 31, dh0 = (lane >> 5) * 32;
      const unsigned short* vp =
          V + (size_t)(b * NDS_ + c * 32 + jj) * 1024 + h * 64 + dh0;
#pragma unroll
      for (int u = 0; u < 4; ++u) {
        short8 vv = *(const short8*)(vp + u * 8);
#pragma unroll
        for (int e = 0; e < 8; ++e)
          Vt[(dh0 + u * 8 + e) * 32 + jj] = (unsigned short)vv[e];
      }
    }
    floatx4 s[2];
#pragma unroll
    for (int nt = 0; nt < 2; ++nt) {
      const unsigned short* kp =
          K + (size_t)(b * NDS_ + c * 32 + nt * 16 + lrow) * 1024 + h * 64 + quad * 8;
      short8 kf0 = *(const short8*)kp;
      short8 kf1 = *(const short8*)(kp + 32);
      floatx4 z = (floatx4){0.f, 0.f, 0.f, 0.f};
      z = __builtin_amdgcn_mfma_f32_16x16x32_bf16(qa0, kf0, z, 0, 0, 0);
      z = __builtin_amdgcn_mfma_f32_16x16x32_bf16(qa1, kf1, z, 0, 0, 0);
      s[nt] = z;
    }
#pragma unroll
    for (int nt = 0; nt < 2; ++nt) {
      int j0 = c * 32 + nt * 16 + lrow;
#pragma unroll
      for (int r = 0; r < 4; ++r) {
        int i = qtile + quad * 4 + r;
        float m = (float)((j0 >= i - 2) + (j0 >= i - 1026));
        // clamp: true scores are O(1); fminf also maps NaN -> 30 (finite guard)
        float p = m * __expf(fminf(s[nt][r] * 0.125f, 30.f));
        denom[r] += p;
        P[(quad * 4 + r) * 32 + nt * 16 + lrow] = f2bf(p);
      }
    }
    short8 pa = *(const short8*)&P[lrow * 32 + quad * 8];
#pragma unroll
    for (int dt = 0; dt < 4; ++dt) {
      short8 vf = *(const short8*)&Vt[(dt * 16 + lrow) * 32 + quad * 8];
      acc_o[dt] = __builtin_amdgcn_mfma_f32_16x16x32_bf16(pa, vf, acc_o[dt], 0, 0, 0);
    }
  }
#pragma unroll
  for (int r = 0; r < 4; ++r) {
    float d = denom[r];
    d += __shfl_xor(d, 1);
    d += __shfl_xor(d, 2);
    d += __shfl_xor(d, 4);
    d += __shfl_xor(d, 8);
    denom[r] = fmaxf(d, 1e-30f);
  }
#pragma unroll
  for (int dt = 0; dt < 4; ++dt)
#pragma unroll
    for (int r = 0; r < 4; ++r) {
      int i = qtile + quad * 4 + r;
      int col = h * 64 + dt * 16 + lrow;
      O[(size_t)(b * QN_ + i) * 1024 + col] = f2bf(acc_o[dt][r] / denom[r]);
    }
}

// ---------- launch ----------
extern "C" void kernel_launch(void* const* d_in, const int* in_sizes, int n_in,
                              void* d_out, int out_size, void* d_ws, size_t ws_size,
                              hipStream_t stream) {
  const void* full = d_in[0];  // [2,2048,1024]
  const void* ds   = d_in[1];  // [2,1024,1024]
  const void* Wq   = d_in[2];  // [1024,1024]
  const void* Wk   = d_in[3];
  const void* Wv   = d_in[4];
  const void* Wo   = d_in[5];
  const void* bo   = d_in[6];  // [1024]

  unsigned short* ws = (unsigned short*)d_ws;
  unsigned short* Qb = ws;                       // [4096,1024]  8 MB
  unsigned short* Kb = ws + 4u * (1u << 20);     // [2048,1024]  4 MB
  unsigned short* Vb = ws + 6u * (1u << 20);     // [2048,1024]  4 MB
  unsigned short* Ab = ws + 8u * (1u << 20);     // [4096,1024]  8 MB
  int* flagp = (int*)(ws + 12u * (1u << 20));    // 4 B @ 24 MB

  dim3 tb(256);
  detect_dtype<<<1, tb, 0, stream>>>((const unsigned short*)Wq, flagp);

  gemm_aw<1, 0><<<dim3(8, 32), tb, 0, stream>>>(full, Wq, Qb, nullptr,
                                                4096, 1024, 1024, flagp);
  gemm_aw<1, 0><<<dim3(8, 16), tb, 0, stream>>>(ds, Wk, Kb, nullptr,
                                                2048, 1024, 1024, flagp);
  gemm_aw<1, 0><<<dim3(8, 16), tb, 0, stream>>>(ds, Wv, Vb, nullptr,
                                                2048, 1024, 1024, flagp);

  attn_kernel<<<dim3(QN_ / 64, B_ * H_), tb, 0, stream>>>(Qb, Kb, Vb, Ab);

  gemm_aw<0, 1><<<dim3(8, 32), tb, 0, stream>>>(Ab, Wo, d_out, bo,
                                                4096, 1024, 1024, flagp);
}

// Round 4
// 326.079 us; speedup vs baseline: 1.3737x; 1.3737x over previous
//
#include <hip/hip_runtime.h>

// ---------- types / helpers ----------
typedef __attribute__((ext_vector_type(8))) short short8;    // 8 x bf16
typedef __attribute__((ext_vector_type(4))) short short4v;   // 4 x bf16
typedef __attribute__((ext_vector_type(4))) float floatx4;   // MFMA acc / 16B fp32
typedef __attribute__((ext_vector_type(4))) unsigned int uint4v;

__device__ __forceinline__ unsigned short f2bf(float f) {
  unsigned u = __float_as_uint(f);
  u += 0x7FFFu + ((u >> 16) & 1u);
  return (unsigned short)(u >> 16);
}
__device__ __forceinline__ float bf2f(unsigned short s) {
  return __uint_as_float(((unsigned)s) << 16);
}
// pack two fp32 -> dword of two bf16 (round-to-nearest, ties away) via v_perm
__device__ __forceinline__ unsigned pack_bf2(float f0, float f1) {
  unsigned a = __float_as_uint(f0) + 0x8000u;
  unsigned b = __float_as_uint(f1) + 0x8000u;
  return __builtin_amdgcn_perm(b, a, 0x07060302u);  // hi16(b)<<16 | hi16(a)... -> [bf(f0)][bf(f1)] in mem
}
// async global->LDS, 16B per lane (dest = wave-uniform base + lane*16)
__device__ __forceinline__ void async16(const unsigned short* g, unsigned short* l) {
  __builtin_amdgcn_global_load_lds(
      (const __attribute__((address_space(1))) unsigned int*)g,
      (__attribute__((address_space(3))) unsigned int*)l, 16, 0, 0);
}

#define B_   2
#define QN_  2048
#define NDS_ 1024
#define H_   16

// ---------- dtype detection (inputs fp32 vs bf16) ----------
__global__ __launch_bounds__(256) void detect_dtype(
    const unsigned short* __restrict__ Wq, int* __restrict__ flag) {
  __shared__ int smax[256];
  int t = threadIdx.x;
  int m = 0;
  for (int i = t; i < 4096; i += 256) {
    int e = (Wq[i] >> 7) & 0xFF;
    m = m > e ? m : e;
  }
  smax[t] = m;
  __syncthreads();
  for (int s = 128; s > 0; s >>= 1) {
    if (t < s) smax[t] = smax[t] > smax[t + s] ? smax[t] : smax[t + s];
    __syncthreads();
  }
  if (t == 0) *flag = (smax[0] >= 0x7F) ? 1 : 0;  // 1 = fp32 inputs
}

// ---------- GEMM: C = A @ W (+bias). BMxBN=BMx128 tile, BK=32 ----------
// QKV=1: BM=128, by in [0,64): Q(by<32,A0/W0) K(by<48,A1/W1) V(A1/W2);
//        A dtype by flag, C bf16 rows by*128 in one combined buffer.
// QKV=0: BM=64, A0 is bf16 (async16-staged), W0/bias flag dtype, C flag dtype.
template <int BM, int QKV>
__global__ __launch_bounds__(256) void gemm_aw(
    const void* __restrict__ A0, const void* __restrict__ A1,
    const void* __restrict__ W0, const void* __restrict__ W1,
    const void* __restrict__ W2, void* __restrict__ C,
    const void* __restrict__ bias, int N, int K, const int* __restrict__ flagp) {
  constexpr int MI = BM / 32;
  __shared__ __align__(16) unsigned short As[BM * 32];
  __shared__ __align__(16) unsigned short Wt[128 * 32];
  const int f32 = *flagp;
  int t = threadIdx.x;
  int lane = t & 63, wave = t >> 6;
  int lrow = lane & 15, quad = lane >> 4;
  int by = blockIdx.y;
  int colBase = blockIdx.x * 128;
  int wr = (wave & 1) * (BM / 2), wc = (wave >> 1) * 64;
  int kr = t & 31, rg = t >> 5;

  const void* A;
  const void* W;
  size_t arow0;
  size_t crow0 = (size_t)by * BM;
  if (QKV) {
    if (by < 32)      { A = A0; W = W0; arow0 = (size_t)by * 128; }
    else if (by < 48) { A = A1; W = W1; arow0 = (size_t)(by - 32) * 128; }
    else              { A = A1; W = W2; arow0 = (size_t)(by - 48) * 128; }
  } else {
    A = A0; W = W0; arow0 = (size_t)by * BM;
  }

  floatx4 acc[MI][4];
#pragma unroll
  for (int mi = 0; mi < MI; ++mi)
#pragma unroll
    for (int ni = 0; ni < 4; ++ni) acc[mi][ni] = (floatx4){0.f, 0.f, 0.f, 0.f};

  for (int k0 = 0; k0 < K; k0 += 32) {
    __syncthreads();
    // ---- A staging ----
    if (QKV) {
#pragma unroll
      for (int it = 0; it < (BM * 32 / 8) / 256; ++it) {
        int linear = it * 256 + t;
        int row = linear >> 2, seg = linear & 3;
        size_t idx = (arow0 + row) * (size_t)K + k0 + seg * 8;
        if (f32) {
          const floatx4* p = (const floatx4*)((const float*)A + idx);
          floatx4 x = p[0], y = p[1];
          uint4v u = {pack_bf2(x[0], x[1]), pack_bf2(x[2], x[3]),
                      pack_bf2(y[0], y[1]), pack_bf2(y[2], y[3])};
          *(uint4v*)&As[linear * 8] = u;
        } else {
          *(short8*)&As[linear * 8] =
              *(const short8*)((const unsigned short*)A + idx);
        }
      }
    } else {
      int row = t >> 2, seg = t & 3;  // 256 chunks exactly
      async16((const unsigned short*)A + (arow0 + row) * (size_t)K + k0 + seg * 8,
              As + t * 8);
    }
    // ---- W staging, transposed: Wt[col][k] = W[k0+k][colBase+col] ----
#pragma unroll
    for (int half = 0; half < 2; ++half) {
      size_t idx = (size_t)(k0 + kr) * N + colBase + rg * 16 + half * 8;
      if (f32) {
        const floatx4* p = (const floatx4*)((const float*)W + idx);
        floatx4 x = p[0], y = p[1];
#pragma unroll
        for (int e = 0; e < 4; ++e) {
          Wt[(rg * 16 + half * 8 + e) * 32 + kr] = f2bf(x[e]);
          Wt[(rg * 16 + half * 8 + 4 + e) * 32 + kr] = f2bf(y[e]);
        }
      } else {
        short8 w = *(const short8*)((const unsigned short*)W + idx);
#pragma unroll
        for (int e = 0; e < 8; ++e)
          Wt[(rg * 16 + half * 8 + e) * 32 + kr] = (unsigned short)w[e];
      }
    }
    __syncthreads();  // also drains async16 vmcnt

    short8 af[MI], bfr[4];
#pragma unroll
    for (int mi = 0; mi < MI; ++mi)
      af[mi] = *(const short8*)&As[(wr + mi * 16 + lrow) * 32 + quad * 8];
#pragma unroll
    for (int ni = 0; ni < 4; ++ni)
      bfr[ni] = *(const short8*)&Wt[(wc + ni * 16 + lrow) * 32 + quad * 8];
#pragma unroll
    for (int mi = 0; mi < MI; ++mi)
#pragma unroll
      for (int ni = 0; ni < 4; ++ni)
        acc[mi][ni] =
            __builtin_amdgcn_mfma_f32_16x16x32_bf16(af[mi], bfr[ni], acc[mi][ni], 0, 0, 0);
  }

#pragma unroll
  for (int mi = 0; mi < MI; ++mi)
#pragma unroll
    for (int ni = 0; ni < 4; ++ni) {
      int col = colBase + wc + ni * 16 + lrow;
      float badd = 0.f;
      if (!QKV)
        badd = f32 ? ((const float*)bias)[col] : bf2f(((const unsigned short*)bias)[col]);
#pragma unroll
      for (int r = 0; r < 4; ++r) {
        size_t row = crow0 + wr + mi * 16 + quad * 4 + r;
        float val = acc[mi][ni][r] + badd;
        size_t oidx = row * (size_t)N + col;
        if (QKV) ((unsigned short*)C)[oidx] = f2bf(val);
        else if (f32) ((float*)C)[oidx] = val;
        else ((unsigned short*)C)[oidx] = f2bf(val);
      }
    }
}

// ---------- in-place per-batch 1024x1024 bf16 transpose (V -> V^T) ----------
__global__ __launch_bounds__(256) void transpose_inplace(unsigned short* V) {
  __shared__ unsigned short ta[64][66], tb[64][66];
  int b = blockIdx.y;
  int p = blockIdx.x;  // 0..135 triangular pair index
  int ti = 0, rem = p;
  while (rem >= 16 - ti) { rem -= 16 - ti; ++ti; }
  int tj = ti + rem;
  unsigned short* Vb = V + (size_t)b * (1024 * 1024);
  int t = threadIdx.x;
  int c4 = (t & 15) * 4, r = t >> 4;
#pragma unroll
  for (int i = 0; i < 4; ++i) {
    int row = r + i * 16;
    *(short4v*)&ta[row][c4] =
        *(const short4v*)&Vb[(size_t)(ti * 64 + row) * 1024 + tj * 64 + c4];
    if (ti != tj)
      *(short4v*)&tb[row][c4] =
          *(const short4v*)&Vb[(size_t)(tj * 64 + row) * 1024 + ti * 64 + c4];
  }
  __syncthreads();
#pragma unroll
  for (int i = 0; i < 4; ++i) {
    int row = r + i * 16;
    short4v wa;
#pragma unroll
    for (int e = 0; e < 4; ++e) wa[e] = ta[c4 + e][row];
    *(short4v*)&Vb[(size_t)(tj * 64 + row) * 1024 + ti * 64 + c4] = wa;
    if (ti != tj) {
      short4v wb;
#pragma unroll
      for (int e = 0; e < 4; ++e) wb[e] = tb[c4 + e][row];
      *(short4v*)&Vb[(size_t)(ti * 64 + row) * 1024 + tj * 64 + c4] = wb;
    }
  }
}

// ---------- attention: unique keys + duplicate multiplier + chunk skip ----------
// m(i,j0) = [j0>=i-2] + [j0>=i-1026]; chunk of 32 kv all-zero for a 16-row wave
// iff 32c+31 < qtile-1026. V supplied TRANSPOSED: Vt[b][dg][kv].
#define PSTR 40  // P row stride (halfwords): 80B = 16B-aligned, 2-way-free banks
__global__ __launch_bounds__(256) void attn_kernel(
    const unsigned short* __restrict__ Q,   // [B*QN][1024]
    const unsigned short* __restrict__ K,   // [B*NDS][1024]
    const unsigned short* __restrict__ Vt,  // [B][1024 dg][1024 kv]
    unsigned short* __restrict__ O) {       // [B*QN][1024]
  __shared__ __align__(16) unsigned short Pl[4][16 * PSTR];
  int t = threadIdx.x, lane = t & 63, wave = t >> 6;
  unsigned short* P = Pl[wave];
  int lrow = lane & 15, quad = lane >> 4;
  int bh = blockIdx.y, b = bh >> 4, h = bh & 15;
  int qtile = blockIdx.x * 64 + wave * 16;

  const unsigned short* qptr =
      Q + (size_t)(b * QN_ + qtile + lrow) * 1024 + h * 64 + quad * 8;
  short8 qa0 = *(const short8*)qptr;
  short8 qa1 = *(const short8*)(qptr + 32);

  floatx4 acc_o[4];
#pragma unroll
  for (int dt = 0; dt < 4; ++dt) acc_o[dt] = (floatx4){0.f, 0.f, 0.f, 0.f};
  float denom[4] = {0.f, 0.f, 0.f, 0.f};

  int c0 = (qtile >= 1058) ? (((qtile - 1058) >> 5) + 1) : 0;
  for (int c = c0; c < NDS_ / 32; ++c) {
    floatx4 s[2];
#pragma unroll
    for (int nt = 0; nt < 2; ++nt) {
      const unsigned short* kp =
          K + (size_t)(b * NDS_ + c * 32 + nt * 16 + lrow) * 1024 + h * 64 + quad * 8;
      short8 kf0 = *(const short8*)kp;
      short8 kf1 = *(const short8*)(kp + 32);
      floatx4 z = (floatx4){0.f, 0.f, 0.f, 0.f};
      z = __builtin_amdgcn_mfma_f32_16x16x32_bf16(qa0, kf0, z, 0, 0, 0);
      z = __builtin_amdgcn_mfma_f32_16x16x32_bf16(qa1, kf1, z, 0, 0, 0);
      s[nt] = z;
    }
#pragma unroll
    for (int nt = 0; nt < 2; ++nt) {
      int j0 = c * 32 + nt * 16 + lrow;
#pragma unroll
      for (int r = 0; r < 4; ++r) {
        int i = qtile + quad * 4 + r;
        float m = (float)((j0 >= i - 2) + (j0 >= i - 1026));
        float p = m * __expf(fminf(s[nt][r] * 0.125f, 30.f));
        denom[r] += p;
        P[(quad * 4 + r) * PSTR + nt * 16 + lrow] = f2bf(p);
      }
    }
    short8 pa = *(const short8*)&P[lrow * PSTR + quad * 8];
#pragma unroll
    for (int dt = 0; dt < 4; ++dt) {
      short8 vf = *(const short8*)&Vt[((size_t)b * 1024 + h * 64 + dt * 16 + lrow) * 1024 +
                                      c * 32 + quad * 8];
      acc_o[dt] = __builtin_amdgcn_mfma_f32_16x16x32_bf16(pa, vf, acc_o[dt], 0, 0, 0);
    }
  }
#pragma unroll
  for (int r = 0; r < 4; ++r) {
    float d = denom[r];
    d += __shfl_xor(d, 1);
    d += __shfl_xor(d, 2);
    d += __shfl_xor(d, 4);
    d += __shfl_xor(d, 8);
    denom[r] = fmaxf(d, 1e-30f);
  }
#pragma unroll
  for (int dt = 0; dt < 4; ++dt)
#pragma unroll
    for (int r = 0; r < 4; ++r) {
      int i = qtile + quad * 4 + r;
      int col = h * 64 + dt * 16 + lrow;
      O[(size_t)(b * QN_ + i) * 1024 + col] = f2bf(acc_o[dt][r] / denom[r]);
    }
}

// ---------- launch ----------
extern "C" void kernel_launch(void* const* d_in, const int* in_sizes, int n_in,
                              void* d_out, int out_size, void* d_ws, size_t ws_size,
                              hipStream_t stream) {
  const void* full = d_in[0];  // [2,2048,1024] fp32|bf16
  const void* ds   = d_in[1];  // [2,1024,1024]
  const void* Wq   = d_in[2];
  const void* Wk   = d_in[3];
  const void* Wv   = d_in[4];
  const void* Wo   = d_in[5];
  const void* bo   = d_in[6];

  // ws (bf16 elems): QKV-out rows 0..8191 = [Qb 4096][Kb 2048][Vb 2048], Ab, flag
  unsigned short* ws = (unsigned short*)d_ws;
  unsigned short* Qb = ws;                    // [0,  4M) elems
  unsigned short* Kb = ws + (4u << 20);       // [4M, 6M)
  unsigned short* Vb = ws + (6u << 20);       // [6M, 8M)  (transposed in place)
  unsigned short* Ab = ws + (8u << 20);       // [8M, 12M)
  int* flagp = (int*)(ws + (12u << 20));      // byte 24M (known-safe footprint)

  dim3 tb(256);
  detect_dtype<<<1, tb, 0, stream>>>((const unsigned short*)Wq, flagp);

  // fused Q/K/V projections: one 512-block launch, C = ws rows 0..8191
  gemm_aw<128, 1><<<dim3(8, 64), tb, 0, stream>>>(full, ds, Wq, Wk, Wv, Qb,
                                                  nullptr, 1024, 1024, flagp);

  transpose_inplace<<<dim3(136, 2), tb, 0, stream>>>(Vb);

  attn_kernel<<<dim3(QN_ / 64, B_ * H_), tb, 0, stream>>>(Qb, Kb, Vb, Ab);

  // out = Ab @ Wo + bo  (BM=64 -> 512 blocks, async16 A staging)
  gemm_aw<64, 0><<<dim3(8, 64), tb, 0, stream>>>(Ab, nullptr, Wo, nullptr, nullptr,
                                                 d_out, bo, 1024, 1024, flagp);
}

// Round 5
// 200.442 us; speedup vs baseline: 2.2347x; 1.6268x over previous
//
#include <hip/hip_runtime.h>

// ---------- types / helpers ----------
typedef __attribute__((ext_vector_type(8))) short short8;    // 8 x bf16
typedef __attribute__((ext_vector_type(4))) short short4v;   // 4 x bf16
typedef __attribute__((ext_vector_type(4))) float floatx4;   // MFMA acc / 16B fp32
typedef __attribute__((ext_vector_type(4))) unsigned int uint4v;
typedef __attribute__((ext_vector_type(2))) unsigned int uint2v;

__device__ __forceinline__ unsigned short f2bf(float f) {
  unsigned u = __float_as_uint(f);
  u += 0x7FFFu + ((u >> 16) & 1u);
  return (unsigned short)(u >> 16);
}
// two fp32 -> dword [bf(f0)][bf(f1)] (validated R4)
__device__ __forceinline__ unsigned pack_bf2(float f0, float f1) {
  unsigned a = __float_as_uint(f0) + 0x8000u;
  unsigned b = __float_as_uint(f1) + 0x8000u;
  return __builtin_amdgcn_perm(b, a, 0x07060302u);
}
__device__ __forceinline__ void async16(const unsigned short* g, unsigned short* l) {
  __builtin_amdgcn_global_load_lds(
      (const __attribute__((address_space(1))) unsigned int*)g,
      (__attribute__((address_space(3))) unsigned int*)l, 16, 0, 0);
}

#define B_   2
#define QN_  2048
#define NDS_ 1024
#define H_   16

// ---------- fp32 -> bf16 elementwise (full activations) ----------
__global__ __launch_bounds__(256) void cvt_bf16(
    const float* __restrict__ in, unsigned short* __restrict__ out) {
  size_t idx = ((size_t)blockIdx.x * 256 + threadIdx.x) * 8;
  floatx4 a = *(const floatx4*)(in + idx);
  floatx4 b = *(const floatx4*)(in + idx + 4);
  uint4v u = {pack_bf2(a[0], a[1]), pack_bf2(a[2], a[3]),
              pack_bf2(b[0], b[1]), pack_bf2(b[2], b[3])};
  *(uint4v*)(out + idx) = u;
}

// ---------- fp32 weights -> bf16 TRANSPOSED (WT[n][k] = W[k][n]) ----------
__global__ __launch_bounds__(256) void cvt_wT(
    const float* __restrict__ Wq, const float* __restrict__ Wk,
    const float* __restrict__ Wv, const float* __restrict__ Wo,
    unsigned short* __restrict__ outbase) {
  const float* W = blockIdx.z == 0 ? Wq : blockIdx.z == 1 ? Wk
                 : blockIdx.z == 2 ? Wv : Wo;
  unsigned short* out = outbase + (size_t)blockIdx.z * (1u << 20);
  __shared__ unsigned short tile[64][65];
  int bi = blockIdx.y, bj = blockIdx.x;
  int c = threadIdx.x & 63, r0 = threadIdx.x >> 6;
#pragma unroll
  for (int i = 0; i < 64; i += 4)
    tile[r0 + i][c] = f2bf(W[(size_t)(bi * 64 + r0 + i) * 1024 + bj * 64 + c]);
  __syncthreads();
#pragma unroll
  for (int i = 0; i < 64; i += 4)
    out[(size_t)(bj * 64 + r0 + i) * 1024 + bi * 64 + c] = tile[c][r0 + i];
}

// ---------- fused QKV GEMM: 128x128 tiles, BK=32, async16 both sides ----------
// by<32: Q rows (A=full_bf async), by in [32,48): K rows (A=ds fp32 pack),
// by in [48,64): V rows (A=ds fp32 pack, epilogue writes Vt transposed).
__global__ __launch_bounds__(256) void gemm_qkv(
    const unsigned short* __restrict__ fullbf, const float* __restrict__ ds,
    const unsigned short* __restrict__ WT,  // [WqT][WkT][WvT], 1M halfwords each
    unsigned short* __restrict__ Qb, unsigned short* __restrict__ Kb,
    unsigned short* __restrict__ Vt) {
  __shared__ __align__(16) unsigned short As[128 * 32];
  __shared__ __align__(16) unsigned short Bs[128 * 32];
  int t = threadIdx.x;
  int lane = t & 63, wave = t >> 6;
  int lrow = lane & 15, quad = lane >> 4;
  int by = blockIdx.y;
  int colBase = blockIdx.x * 128;
  int wr = (wave & 1) * 64, wc = (wave >> 1) * 64;

  int sel = (by < 32) ? 0 : (by < 48 ? 1 : 2);
  const unsigned short* Wt = WT + (size_t)sel * (1u << 20);
  size_t arow0 = (sel == 0) ? (size_t)by * 128
                            : (size_t)(by - (sel == 1 ? 32 : 48)) * 128;

  floatx4 acc[4][4];
#pragma unroll
  for (int mi = 0; mi < 4; ++mi)
#pragma unroll
    for (int ni = 0; ni < 4; ++ni) acc[mi][ni] = (floatx4){0.f, 0.f, 0.f, 0.f};

  for (int k0 = 0; k0 < 1024; k0 += 32) {
    __syncthreads();
    if (sel == 0) {
#pragma unroll
      for (int it = 0; it < 2; ++it) {
        int linear = it * 256 + t;
        int row = linear >> 2, seg = linear & 3;
        async16(fullbf + (arow0 + row) * 1024 + k0 + seg * 8, As + linear * 8);
      }
    } else {
#pragma unroll
      for (int it = 0; it < 2; ++it) {
        int linear = it * 256 + t;
        int row = linear >> 2, seg = linear & 3;
        const float* p = ds + (arow0 + row) * 1024 + k0 + seg * 8;
        floatx4 x = *(const floatx4*)p, y = *(const floatx4*)(p + 4);
        uint4v u = {pack_bf2(x[0], x[1]), pack_bf2(x[2], x[3]),
                    pack_bf2(y[0], y[1]), pack_bf2(y[2], y[3])};
        *(uint4v*)&As[linear * 8] = u;
      }
    }
#pragma unroll
    for (int it = 0; it < 2; ++it) {
      int linear = it * 256 + t;
      int row = linear >> 2, seg = linear & 3;
      async16(Wt + (size_t)(colBase + row) * 1024 + k0 + seg * 8, Bs + linear * 8);
    }
    __syncthreads();

    short8 af[4], bfr[4];
#pragma unroll
    for (int mi = 0; mi < 4; ++mi)
      af[mi] = *(const short8*)&As[(wr + mi * 16 + lrow) * 32 + quad * 8];
#pragma unroll
    for (int ni = 0; ni < 4; ++ni)
      bfr[ni] = *(const short8*)&Bs[(wc + ni * 16 + lrow) * 32 + quad * 8];
#pragma unroll
    for (int mi = 0; mi < 4; ++mi)
#pragma unroll
      for (int ni = 0; ni < 4; ++ni)
        acc[mi][ni] =
            __builtin_amdgcn_mfma_f32_16x16x32_bf16(af[mi], bfr[ni], acc[mi][ni], 0, 0, 0);
  }

#pragma unroll
  for (int mi = 0; mi < 4; ++mi)
#pragma unroll
    for (int ni = 0; ni < 4; ++ni) {
      int col = colBase + wc + ni * 16 + lrow;
      if (sel == 2) {
        size_t r0g = arow0 + wr + mi * 16 + quad * 4;  // global kv row (4 consec)
        size_t b = r0g >> 10, kv = r0g & 1023;
        short4v pk;
#pragma unroll
        for (int r = 0; r < 4; ++r) pk[r] = (short)f2bf(acc[mi][ni][r]);
        *(short4v*)&Vt[b * (1u << 20) + (size_t)col * 1024 + kv] = pk;
      } else {
        unsigned short* C = (sel == 0) ? Qb : Kb;
#pragma unroll
        for (int r = 0; r < 4; ++r) {
          size_t row = arow0 + wr + mi * 16 + quad * 4 + r;
          C[row * 1024 + col] = f2bf(acc[mi][ni][r]);
        }
      }
    }
}

// ---------- attention v3: block-shared dbuf staging + transposed scores ----------
// S^T = K Q^T (C-layout -> lane holds P[q=lrow][k=quad*4+r], k-contiguous).
// PV: A=P (LDS b64-write/b128-read round trip), B=V from shared Vs.
#define PSTR 40
__global__ __launch_bounds__(256) void attn_kernel(
    const unsigned short* __restrict__ Q,   // [4096][1024] bf16
    const unsigned short* __restrict__ K,   // [2048][1024] bf16
    const unsigned short* __restrict__ V,   // Vt [B][1024 d][1024 kv] bf16
    unsigned short* __restrict__ O) {       // [4096][1024] bf16
  __shared__ __align__(16) unsigned short Ks[2][32 * 64];
  __shared__ __align__(16) unsigned short Vs[2][64 * 32];
  __shared__ __align__(16) unsigned short Pl[4][16 * PSTR];
  int t = threadIdx.x, lane = t & 63, wave = t >> 6;
  int lrow = lane & 15, quad = lane >> 4;
  int bh = blockIdx.y, b = bh >> 4, h = bh & 15;
  int q0 = blockIdx.x * 64, qtile = q0 + wave * 16;

  // Q as B-operand: n=q=lrow, k=d=quad*8+j (+32)
  const unsigned short* qp =
      Q + (size_t)(b * QN_ + qtile + lrow) * 1024 + h * 64 + quad * 8;
  short8 qb0 = *(const short8*)qp;
  short8 qb1 = *(const short8*)(qp + 32);

  // staging sources (chunk term added per iteration)
  const unsigned short* ksrc =
      K + (size_t)(b * NDS_ + (t >> 3)) * 1024 + h * 64 + (t & 7) * 8;
  const unsigned short* vsrc =
      V + ((size_t)b * 1024 + h * 64 + (t >> 2)) * 1024 + (t & 3) * 8;

  int c0 = (q0 >= 1058) ? (((q0 - 1058) >> 5) + 1) : 0;
  async16(ksrc + (size_t)c0 * 32 * 1024, &Ks[0][t * 8]);
  async16(vsrc + c0 * 32, &Vs[0][t * 8]);

  floatx4 acc_o[4];
#pragma unroll
  for (int dt = 0; dt < 4; ++dt) acc_o[dt] = (floatx4){0.f, 0.f, 0.f, 0.f};
  float denom = 0.f;
  int t1 = qtile + lrow - 2, t2 = qtile + lrow - 1026;  // per-lane q thresholds
  unsigned short* P = Pl[wave];
  int buf = 0;

  for (int c = c0; c < 32; ++c) {
    __syncthreads();  // chunk c staged; prior reads of buf^1 complete
    if (c + 1 < 32) {
      async16(ksrc + (size_t)(c + 1) * 32 * 1024, &Ks[buf ^ 1][t * 8]);
      async16(vsrc + (c + 1) * 32, &Vs[buf ^ 1][t * 8]);
    }
    int cb = c * 32;
#pragma unroll
    for (int nt = 0; nt < 2; ++nt) {
      const unsigned short* kb = &Ks[buf][(nt * 16 + lrow) * 64 + quad * 8];
      short8 ka0 = *(const short8*)kb;
      short8 ka1 = *(const short8*)(kb + 32);
      floatx4 z = (floatx4){0.f, 0.f, 0.f, 0.f};
      z = __builtin_amdgcn_mfma_f32_16x16x32_bf16(ka0, qb0, z, 0, 0, 0);
      z = __builtin_amdgcn_mfma_f32_16x16x32_bf16(ka1, qb1, z, 0, 0, 0);
      float p[4];
#pragma unroll
      for (int r = 0; r < 4; ++r) {
        int j0 = cb + nt * 16 + quad * 4 + r;
        float m = (j0 >= t1 ? 1.f : 0.f) + (j0 >= t2 ? 1.f : 0.f);
        p[r] = m * __expf(z[r] * 0.125f);
        denom += p[r];
      }
      uint2v pw = {pack_bf2(p[0], p[1]), pack_bf2(p[2], p[3])};
      *(uint2v*)&P[lrow * PSTR + nt * 16 + quad * 4] = pw;
    }
    short8 pa = *(const short8*)&P[lrow * PSTR + quad * 8];
#pragma unroll
    for (int dt = 0; dt < 4; ++dt) {
      short8 vf = *(const short8*)&Vs[buf][(dt * 16 + lrow) * 32 + quad * 8];
      acc_o[dt] = __builtin_amdgcn_mfma_f32_16x16x32_bf16(pa, vf, acc_o[dt], 0, 0, 0);
    }
    buf ^= 1;
  }
  // denom(q=lrow): sum across quads, then redistribute to epilogue rows
  denom += __shfl_xor(denom, 16);
  denom += __shfl_xor(denom, 32);
  float dd[4];
#pragma unroll
  for (int r = 0; r < 4; ++r) dd[r] = __shfl(denom, quad * 4 + r);
#pragma unroll
  for (int dt = 0; dt < 4; ++dt)
#pragma unroll
    for (int r = 0; r < 4; ++r) {
      int i = qtile + quad * 4 + r;
      int col = h * 64 + dt * 16 + lrow;
      O[(size_t)(b * QN_ + i) * 1024 + col] = f2bf(acc_o[dt][r] / dd[r]);
    }
}

// ---------- O GEMM: out = Ab @ WoT^T + bo, BM=64, async16 both sides ----------
__global__ __launch_bounds__(256) void gemm_o(
    const unsigned short* __restrict__ Ab, const unsigned short* __restrict__ WoT,
    const float* __restrict__ bo, float* __restrict__ out) {
  __shared__ __align__(16) unsigned short As[64 * 32];
  __shared__ __align__(16) unsigned short Bs[128 * 32];
  int t = threadIdx.x;
  int lane = t & 63, wave = t >> 6;
  int lrow = lane & 15, quad = lane >> 4;
  size_t rowBase = (size_t)blockIdx.y * 64;
  int colBase = blockIdx.x * 128;
  int wr = (wave & 1) * 32, wc = (wave >> 1) * 64;

  floatx4 acc[2][4];
#pragma unroll
  for (int mi = 0; mi < 2; ++mi)
#pragma unroll
    for (int ni = 0; ni < 4; ++ni) acc[mi][ni] = (floatx4){0.f, 0.f, 0.f, 0.f};

  for (int k0 = 0; k0 < 1024; k0 += 32) {
    __syncthreads();
    {
      int row = t >> 2, seg = t & 3;
      async16(Ab + (rowBase + row) * 1024 + k0 + seg * 8, As + t * 8);
    }
#pragma unroll
    for (int it = 0; it < 2; ++it) {
      int linear = it * 256 + t;
      int row = linear >> 2, seg = linear & 3;
      async16(WoT + (size_t)(colBase + row) * 1024 + k0 + seg * 8, Bs + linear * 8);
    }
    __syncthreads();

    short8 af[2], bfr[4];
#pragma unroll
    for (int mi = 0; mi < 2; ++mi)
      af[mi] = *(const short8*)&As[(wr + mi * 16 + lrow) * 32 + quad * 8];
#pragma unroll
    for (int ni = 0; ni < 4; ++ni)
      bfr[ni] = *(const short8*)&Bs[(wc + ni * 16 + lrow) * 32 + quad * 8];
#pragma unroll
    for (int mi = 0; mi < 2; ++mi)
#pragma unroll
      for (int ni = 0; ni < 4; ++ni)
        acc[mi][ni] =
            __builtin_amdgcn_mfma_f32_16x16x32_bf16(af[mi], bfr[ni], acc[mi][ni], 0, 0, 0);
  }

#pragma unroll
  for (int mi = 0; mi < 2; ++mi)
#pragma unroll
    for (int ni = 0; ni < 4; ++ni) {
      int col = colBase + wc + ni * 16 + lrow;
      float badd = bo[col];
#pragma unroll
      for (int r = 0; r < 4; ++r) {
        size_t row = rowBase + wr + mi * 16 + quad * 4 + r;
        out[row * 1024 + col] = acc[mi][ni][r] + badd;
      }
    }
}

// ---------- launch ----------
extern "C" void kernel_launch(void* const* d_in, const int* in_sizes, int n_in,
                              void* d_out, int out_size, void* d_ws, size_t ws_size,
                              hipStream_t stream) {
  const float* full = (const float*)d_in[0];  // [2,2048,1024] fp32
  const float* ds   = (const float*)d_in[1];  // [2,1024,1024] fp32
  const float* Wq   = (const float*)d_in[2];
  const float* Wk   = (const float*)d_in[3];
  const float* Wv   = (const float*)d_in[4];
  const float* Wo   = (const float*)d_in[5];
  const float* bo   = (const float*)d_in[6];
  float* out = (float*)d_out;

  // ws layout (halfwords), 32 MB total:
  unsigned short* ws = (unsigned short*)d_ws;
  unsigned short* Qb      = ws;                     // [0,4M)   4096x1024
  unsigned short* Kb      = ws + (4u << 20);        // [4M,6M)  2048x1024
  unsigned short* Vt      = ws + (6u << 20);        // [6M,8M)  [B][1024][1024]
  unsigned short* Ab      = ws + (8u << 20);        // [8M,12M) 4096x1024 (aliases full_bf)
  unsigned short* full_bf = Ab;                     // dead after gemm_qkv
  unsigned short* WT      = ws + (12u << 20);       // [12M,16M) WqT WkT WvT WoT
  unsigned short* WoT     = WT + 3u * (1u << 20);

  dim3 tb(256);
  cvt_bf16<<<2048, tb, 0, stream>>>(full, full_bf);
  cvt_wT<<<dim3(16, 16, 4), tb, 0, stream>>>(Wq, Wk, Wv, Wo, WT);
  gemm_qkv<<<dim3(8, 64), tb, 0, stream>>>(full_bf, ds, WT, Qb, Kb, Vt);
  attn_kernel<<<dim3(QN_ / 64, B_ * H_), tb, 0, stream>>>(Qb, Kb, Vt, Ab);
  gemm_o<<<dim3(8, 64), tb, 0, stream>>>(Ab, WoT, bo, out);
}